// Round 1
// baseline (4095.829 us; speedup 1.0000x reference)
//
#include <hip/hip_runtime.h>
#include <hip/hip_bf16.h>

#define D 128

__device__ __forceinline__ void atomAddF(float* p, float v) {
    unsafeAtomicAdd(p, v);   // global_atomic_add_f32 on gfx950
}

// ---------------- scatter: agg[dst] += xsrc[src], rows of 128 floats ----------------
// one thread per (edge, 4-col group): float4 gather + 4 atomic adds
__global__ void scatter_rows(const float* __restrict__ xsrc,
                             const int* __restrict__ src,
                             const int* __restrict__ dst,
                             float* __restrict__ agg, int E) {
    long tid = (long)blockIdx.x * blockDim.x + threadIdx.x;
    int e = (int)(tid >> 5);
    if (e >= E) return;
    int q = ((int)tid & 31) * 4;
    int s = src[e];
    int d = dst[e];
    const float4 v = *(const float4*)(xsrc + (long)s * D + q);
    float* p = agg + (long)d * D + q;
    atomAddF(p + 0, v.x);
    atomAddF(p + 1, v.y);
    atomAddF(p + 2, v.z);
    atomAddF(p + 3, v.w);
}

// ---------------- combine W_root_adj + W_root_groups and biases ----------------
__global__ void combine_wb(const float* __restrict__ Wa, const float* __restrict__ Wg,
                           float* __restrict__ Wsum,
                           const float* __restrict__ ba, const float* __restrict__ bg,
                           float* __restrict__ bsum) {
    int i = blockIdx.x * blockDim.x + threadIdx.x;
    if (i < D * D) Wsum[i] = Wa[i] + Wg[i];
    if (i < D) bsum[i] = ba[i] + bg[i];
}

// ---------------- multi-term GEMM: out = sum_t A_t @ W_t + bias, plus col stats ----------------
// tile: 128 rows x 128 cols per block, 256 threads, 8x8 outputs/thread
__launch_bounds__(256, 2)
__global__ void gemm_multi(int N,
                           const float* __restrict__ A0, const float* __restrict__ W0,
                           const float* __restrict__ A1, const float* __restrict__ W1,
                           const float* __restrict__ A2, const float* __restrict__ W2,
                           int nTerms,
                           const float* __restrict__ bias,
                           float* __restrict__ out,
                           float* __restrict__ gsum, float* __restrict__ gsq) {
    __shared__ float smem[2048];          // sA [8][128] | sW [8][128]; epilogue reuses all 2048
    float* sA = smem;
    float* sW = smem + 1024;

    const int tx = threadIdx.x;
    const int row0 = blockIdx.x * 128;
    const int r = (tx >> 4) * 8;          // row offset within tile
    const int c = (tx & 15) * 8;          // col offset within tile

    float acc[8][8];
#pragma unroll
    for (int i = 0; i < 8; ++i)
#pragma unroll
        for (int j = 0; j < 8; ++j) acc[i][j] = 0.f;

    const float* As[3] = {A0, A1, A2};
    const float* Ws[3] = {W0, W1, W2};

    const int lrow  = tx >> 1;            // 0..127 (A staging row)
    const int lhalf = tx & 1;             // which float4 of the 8-wide k chunk
    const int wrow  = tx >> 5;            // 0..7   (W staging k-row)
    const int wcol  = (tx & 31) * 4;      // 0..124

    for (int t = 0; t < nTerms; ++t) {
        const float* __restrict__ A = As[t];
        const float* __restrict__ W = Ws[t];
        for (int k0 = 0; k0 < D; k0 += 8) {
            // stage A chunk transposed: sA[k][row]
            float4 av = make_float4(0.f, 0.f, 0.f, 0.f);
            int garow = row0 + lrow;
            if (garow < N) av = *(const float4*)(A + (long)garow * D + k0 + lhalf * 4);
            sA[(lhalf * 4 + 0) * 128 + lrow] = av.x;
            sA[(lhalf * 4 + 1) * 128 + lrow] = av.y;
            sA[(lhalf * 4 + 2) * 128 + lrow] = av.z;
            sA[(lhalf * 4 + 3) * 128 + lrow] = av.w;
            // stage W chunk: sW[k][col], coalesced
            const float4 wv = *(const float4*)(W + (long)(k0 + wrow) * D + wcol);
            *(float4*)(sW + wrow * 128 + wcol) = wv;
            __syncthreads();
#pragma unroll
            for (int k = 0; k < 8; ++k) {
                const float4 a0 = *(const float4*)(sA + k * 128 + r);
                const float4 a1 = *(const float4*)(sA + k * 128 + r + 4);
                const float4 w0 = *(const float4*)(sW + k * 128 + c);
                const float4 w1 = *(const float4*)(sW + k * 128 + c + 4);
                float a[8] = {a0.x, a0.y, a0.z, a0.w, a1.x, a1.y, a1.z, a1.w};
                float w[8] = {w0.x, w0.y, w0.z, w0.w, w1.x, w1.y, w1.z, w1.w};
#pragma unroll
                for (int i = 0; i < 8; ++i)
#pragma unroll
                    for (int j = 0; j < 8; ++j)
                        acc[i][j] = fmaf(a[i], w[j], acc[i][j]);
            }
            __syncthreads();
        }
    }

    // epilogue: bias, store pre-norm output, per-column partial stats
    float bvals[8];
#pragma unroll
    for (int j = 0; j < 8; ++j) bvals[j] = bias[c + j];

    float psum[8], psq[8];
#pragma unroll
    for (int j = 0; j < 8; ++j) { psum[j] = 0.f; psq[j] = 0.f; }

#pragma unroll
    for (int i = 0; i < 8; ++i) {
        int row = row0 + r + i;
        if (row < N) {
#pragma unroll
            for (int j = 0; j < 8; ++j) {
                float v = acc[i][j] + bvals[j];
                acc[i][j] = v;
                psum[j] += v;
                psq[j] += v * v;
            }
            *(float4*)(out + (long)row * D + c)     = make_float4(acc[i][0], acc[i][1], acc[i][2], acc[i][3]);
            *(float4*)(out + (long)row * D + c + 4) = make_float4(acc[i][4], acc[i][5], acc[i][6], acc[i][7]);
        }
    }

    // block-level reduction of column stats, then one atomic per column
    float* red = smem;  // 2048 floats
#pragma unroll
    for (int j = 0; j < 8; ++j) red[tx * 8 + j] = psum[j];
    __syncthreads();
    if (tx < 128) {
        int g = tx >> 3, j = tx & 7;
        float s = 0.f;
#pragma unroll
        for (int i = 0; i < 16; ++i) s += red[(g + 16 * i) * 8 + j];
        atomAddF(&gsum[tx], s);
    }
    __syncthreads();
#pragma unroll
    for (int j = 0; j < 8; ++j) red[tx * 8 + j] = psq[j];
    __syncthreads();
    if (tx < 128) {
        int g = tx >> 3, j = tx & 7;
        float s = 0.f;
#pragma unroll
        for (int i = 0; i < 16; ++i) s += red[(g + 16 * i) * 8 + j];
        atomAddF(&gsq[tx], s);
    }
}

// ---------------- stats -> scale/shift ----------------
__global__ void finalize_stats(const float* __restrict__ stats,  // [sumV,sqV,sumC,sqC] x128
                               const float* __restrict__ wv, const float* __restrict__ bv, const float* __restrict__ msv,
                               const float* __restrict__ wc, const float* __restrict__ bc, const float* __restrict__ msc,
                               int Nvar, int Ncon,
                               float* __restrict__ scale_var, float* __restrict__ shift_var,
                               float* __restrict__ scale_con, float* __restrict__ shift_con) {
    int tx = threadIdx.x;
    if (tx < 128) {
        float n = (float)Nvar;
        float mu = stats[tx] / n;
        float ex2 = stats[128 + tx] / n;
        float ms = msv[tx];
        float var = ex2 - 2.f * ms * mu * mu + ms * ms * mu * mu;
        float istd = rsqrtf(var + 1e-5f);
        float sc = wv[tx] * istd;
        scale_var[tx] = sc;
        shift_var[tx] = bv[tx] - sc * ms * mu;
    } else if (tx < 256) {
        int t = tx - 128;
        float n = (float)Ncon;
        float mu = stats[256 + t] / n;
        float ex2 = stats[384 + t] / n;
        float ms = msc[t];
        float var = ex2 - 2.f * ms * mu * mu + ms * ms * mu * mu;
        float istd = rsqrtf(var + 1e-5f);
        float sc = wc[t] * istd;
        scale_con[t] = sc;
        shift_con[t] = bc[t] - sc * ms * mu;
    }
}

// ---------------- in-place normalize + relu ----------------
__global__ void norm_relu(float* __restrict__ buf,
                          const float* __restrict__ scale, const float* __restrict__ shift,
                          long nvec) {
    long i = (long)blockIdx.x * blockDim.x + threadIdx.x;
    if (i >= nvec) return;
    int q = ((int)i & 31) * 4;
    float4 v = *(float4*)(buf + i * 4);
    float4 o;
    o.x = fmaxf(0.f, v.x * scale[q + 0] + shift[q + 0]);
    o.y = fmaxf(0.f, v.y * scale[q + 1] + shift[q + 1]);
    o.z = fmaxf(0.f, v.z * scale[q + 2] + shift[q + 2]);
    o.w = fmaxf(0.f, v.w * scale[q + 3] + shift[q + 3]);
    *(float4*)(buf + i * 4) = o;
}

extern "C" void kernel_launch(void* const* d_in, const int* in_sizes, int n_in,
                              void* d_out, int out_size, void* d_ws, size_t ws_size,
                              hipStream_t stream) {
    const float* x_var = (const float*)d_in[0];
    const float* x_con = (const float*)d_in[1];
    const float* x_reg = (const float*)d_in[2];
    const int* src_adj = (const int*)d_in[3];
    const int* dst_adj = (const int*)d_in[4];
    const int* src_t   = (const int*)d_in[5];
    const int* dst_t   = (const int*)d_in[6];
    const int* src_g   = (const int*)d_in[7];
    const int* dst_g   = (const int*)d_in[8];
    const float* W_rel_adj  = (const float*)d_in[9];
    const float* b_adj      = (const float*)d_in[10];
    const float* W_root_adj = (const float*)d_in[11];
    const float* W_rel_t    = (const float*)d_in[12];
    const float* b_t        = (const float*)d_in[13];
    const float* W_root_t   = (const float*)d_in[14];
    const float* W_rel_g    = (const float*)d_in[15];
    const float* b_g        = (const float*)d_in[16];
    const float* W_root_g   = (const float*)d_in[17];
    const float* gnw_v  = (const float*)d_in[18];
    const float* gnb_v  = (const float*)d_in[19];
    const float* gnms_v = (const float*)d_in[20];
    const float* gnw_c  = (const float*)d_in[21];
    const float* gnb_c  = (const float*)d_in[22];
    const float* gnms_c = (const float*)d_in[23];

    const int Nvar = in_sizes[0] / D;
    const int Ncon = in_sizes[1] / D;
    const int Eadj = in_sizes[3];
    const int Et   = in_sizes[5];
    const int Eg   = in_sizes[7];

    float* ws = (float*)d_ws;
    float* agg_adj = ws;
    float* agg_g   = agg_adj + (size_t)Nvar * D;
    float* agg_t   = agg_g + (size_t)Nvar * D;
    float* stats   = agg_t + (size_t)Ncon * D;   // 512 floats: sumV, sqV, sumC, sqC
    float* scale_var = stats + 512;
    float* shift_var = scale_var + 128;
    float* scale_con = shift_var + 128;
    float* shift_con = scale_con + 128;
    float* Wsum = shift_con + 128;               // 16384 floats
    float* bsum = Wsum + D * D;                  // 128 floats

    size_t aggBytes = ((size_t)Nvar * 2 + (size_t)Ncon) * D * sizeof(float);
    hipMemsetAsync(d_ws, 0, aggBytes, stream);
    hipMemsetAsync(stats, 0, 512 * sizeof(float), stream);

    combine_wb<<<64, 256, 0, stream>>>(W_root_adj, W_root_g, Wsum, b_adj, b_g, bsum);

    {
        long T = (long)Eadj * 32;
        scatter_rows<<<(int)((T + 255) / 256), 256, 0, stream>>>(x_var, src_adj, dst_adj, agg_adj, Eadj);
    }
    {
        long T = (long)Eg * 32;
        scatter_rows<<<(int)((T + 255) / 256), 256, 0, stream>>>(x_reg, src_g, dst_g, agg_g, Eg);
    }
    {
        long T = (long)Et * 32;
        scatter_rows<<<(int)((T + 255) / 256), 256, 0, stream>>>(x_var, src_t, dst_t, agg_t, Et);
    }

    float* out_var = (float*)d_out;
    float* out_con = out_var + (size_t)Nvar * D;

    gemm_multi<<<(Nvar + 127) / 128, 256, 0, stream>>>(Nvar,
        agg_adj, W_rel_adj, agg_g, W_rel_g, x_var, Wsum, 3,
        bsum, out_var, stats, stats + 128);
    gemm_multi<<<(Ncon + 127) / 128, 256, 0, stream>>>(Ncon,
        agg_t, W_rel_t, x_con, W_root_t, nullptr, nullptr, 2,
        b_t, out_con, stats + 256, stats + 384);

    finalize_stats<<<1, 256, 0, stream>>>(stats,
        gnw_v, gnb_v, gnms_v, gnw_c, gnb_c, gnms_c,
        Nvar, Ncon, scale_var, shift_var, scale_con, shift_con);

    {
        long nvec = (long)Nvar * 32;
        norm_relu<<<(int)((nvec + 255) / 256), 256, 0, stream>>>(out_var, scale_var, shift_var, nvec);
    }
    {
        long nvec = (long)Ncon * 32;
        norm_relu<<<(int)((nvec + 255) / 256), 256, 0, stream>>>(out_con, scale_con, shift_con, nvec);
    }
}

// Round 2
// 1375.499 us; speedup vs baseline: 2.9777x; 2.9777x over previous
//
#include <hip/hip_runtime.h>
#include <hip/hip_bf16.h>

#define D 128
#define CAP 32

__device__ __forceinline__ void atomAddF(float* p, float v) {
    unsafeAtomicAdd(p, v);
}

// ---------------- combine W_root_adj + W_root_groups and biases ----------------
__global__ void combine_wb(const float* __restrict__ Wa, const float* __restrict__ Wg,
                           float* __restrict__ Wsum,
                           const float* __restrict__ ba, const float* __restrict__ bg,
                           float* __restrict__ bsum) {
    int i = blockIdx.x * blockDim.x + threadIdx.x;
    if (i < D * D) Wsum[i] = Wa[i] + Wg[i];
    if (i < D) bsum[i] = ba[i] + bg[i];
}

// ---------------- bucket build: per-dst edge lists, fixed capacity ----------------
__global__ void fill_buckets(const int* __restrict__ src, const int* __restrict__ dst, int E,
                             int* __restrict__ cnt, int* __restrict__ buckets,
                             int* __restrict__ ovf, int* __restrict__ ovf_cnt) {
    int e = blockIdx.x * blockDim.x + threadIdx.x;
    if (e >= E) return;
    int d = dst[e];
    int p = atomicAdd(&cnt[d], 1);
    if (p < CAP) buckets[(long)d * CAP + p] = src[e];
    else         ovf[atomicAdd(ovf_cnt, 1)] = e;     // ovf sized E: can't overflow
}

// ---------------- pull-aggregate: out[d] += sum_{e: dst==d} y[src_e] ----------------
// one wave per dst row; lane holds 2 columns (float2)
__launch_bounds__(256)
__global__ void pull_add(const float* __restrict__ y, const int* __restrict__ cnt,
                         const int* __restrict__ buckets, float* __restrict__ out, int N) {
    int wid = (int)(((long)blockIdx.x * blockDim.x + threadIdx.x) >> 6);
    int lane = threadIdx.x & 63;
    if (wid >= N) return;
    int m = cnt[wid];
    if (m > CAP) m = CAP;
    int idx = (lane < m) ? buckets[(long)wid * CAP + lane] : 0;
    float accx = 0.f, accy = 0.f;
    for (int j = 0; j < m; ++j) {
        int s = __shfl(idx, j, 64);
        const float2 v = *(const float2*)(y + (long)s * D + lane * 2);
        accx += v.x;
        accy += v.y;
    }
    float2* po = (float2*)(out + (long)wid * D) + lane;
    float2 o = *po;
    o.x += accx;
    o.y += accy;
    *po = o;
}

// ---------------- overflow edges (expected count 0): atomic adds ----------------
__global__ void overflow_scatter(const int* __restrict__ src, const int* __restrict__ dst,
                                 const int* __restrict__ ovf, const int* __restrict__ ovf_cnt,
                                 const float* __restrict__ y, float* __restrict__ out) {
    long n = (long)(*ovf_cnt) * 32;
    for (long t = (long)blockIdx.x * blockDim.x + threadIdx.x; t < n;
         t += (long)gridDim.x * blockDim.x) {
        int i = (int)(t >> 5);
        int q = ((int)t & 31) * 4;
        int e = ovf[i];
        int s = src[e], d = dst[e];
        const float4 v = *(const float4*)(y + (long)s * D + q);
        float* p = out + (long)d * D + q;
        atomAddF(p + 0, v.x);
        atomAddF(p + 1, v.y);
        atomAddF(p + 2, v.z);
        atomAddF(p + 3, v.w);
    }
}

// ---------------- GEMM: out = A @ W (+bias) ----------------
// tile: 128 rows x 128 cols per block, 256 threads, 8x8 outputs/thread
__launch_bounds__(256, 2)
__global__ void gemm_nn(int N,
                        const float* __restrict__ A, const float* __restrict__ W,
                        const float* __restrict__ bias,   // may be null
                        float* __restrict__ out) {
    __shared__ float smem[2048];          // sA [8][128] | sW [8][128]
    float* sA = smem;
    float* sW = smem + 1024;

    const int tx = threadIdx.x;
    const int row0 = blockIdx.x * 128;
    const int r = (tx >> 4) * 8;
    const int c = (tx & 15) * 8;

    float acc[8][8];
#pragma unroll
    for (int i = 0; i < 8; ++i)
#pragma unroll
        for (int j = 0; j < 8; ++j) acc[i][j] = 0.f;

    const int lrow  = tx >> 1;
    const int lhalf = tx & 1;
    const int wrow  = tx >> 5;
    const int wcol  = (tx & 31) * 4;

    for (int k0 = 0; k0 < D; k0 += 8) {
        float4 av = make_float4(0.f, 0.f, 0.f, 0.f);
        int garow = row0 + lrow;
        if (garow < N) av = *(const float4*)(A + (long)garow * D + k0 + lhalf * 4);
        sA[(lhalf * 4 + 0) * 128 + lrow] = av.x;
        sA[(lhalf * 4 + 1) * 128 + lrow] = av.y;
        sA[(lhalf * 4 + 2) * 128 + lrow] = av.z;
        sA[(lhalf * 4 + 3) * 128 + lrow] = av.w;
        const float4 wv = *(const float4*)(W + (long)(k0 + wrow) * D + wcol);
        *(float4*)(sW + wrow * 128 + wcol) = wv;
        __syncthreads();
#pragma unroll
        for (int k = 0; k < 8; ++k) {
            const float4 a0 = *(const float4*)(sA + k * 128 + r);
            const float4 a1 = *(const float4*)(sA + k * 128 + r + 4);
            const float4 w0 = *(const float4*)(sW + k * 128 + c);
            const float4 w1 = *(const float4*)(sW + k * 128 + c + 4);
            float a[8] = {a0.x, a0.y, a0.z, a0.w, a1.x, a1.y, a1.z, a1.w};
            float w[8] = {w0.x, w0.y, w0.z, w0.w, w1.x, w1.y, w1.z, w1.w};
#pragma unroll
            for (int i = 0; i < 8; ++i)
#pragma unroll
                for (int j = 0; j < 8; ++j)
                    acc[i][j] = fmaf(a[i], w[j], acc[i][j]);
        }
        __syncthreads();
    }

    float bvals[8];
#pragma unroll
    for (int j = 0; j < 8; ++j) bvals[j] = bias ? bias[c + j] : 0.f;

#pragma unroll
    for (int i = 0; i < 8; ++i) {
        int row = row0 + r + i;
        if (row < N) {
            *(float4*)(out + (long)row * D + c) =
                make_float4(acc[i][0] + bvals[0], acc[i][1] + bvals[1],
                            acc[i][2] + bvals[2], acc[i][3] + bvals[3]);
            *(float4*)(out + (long)row * D + c + 4) =
                make_float4(acc[i][4] + bvals[4], acc[i][5] + bvals[5],
                            acc[i][6] + bvals[6], acc[i][7] + bvals[7]);
        }
    }
}

// ---------------- per-column sum / sumsq over a row-major [N,128] buffer ----------------
__global__ void col_stats(const float* __restrict__ buf, int Nrows,
                          float* __restrict__ gsum, float* __restrict__ gsq) {
    __shared__ float red[1024];
    const int tx = threadIdx.x;
    const int cg = (tx & 31) * 4;        // column group
    const int rl = tx >> 5;              // 0..7 local row
    float4 s = make_float4(0.f, 0.f, 0.f, 0.f);
    float4 q = make_float4(0.f, 0.f, 0.f, 0.f);
    for (long r = (long)blockIdx.x * 8 + rl; r < Nrows; r += (long)gridDim.x * 8) {
        float4 v = *(const float4*)(buf + r * D + cg);
        s.x += v.x; s.y += v.y; s.z += v.z; s.w += v.w;
        q.x += v.x * v.x; q.y += v.y * v.y; q.z += v.z * v.z; q.w += v.w * v.w;
    }
    *(float4*)(red + tx * 4) = s;
    __syncthreads();
    if (tx < 32) {
        float4 t = make_float4(0.f, 0.f, 0.f, 0.f);
#pragma unroll
        for (int i = 0; i < 8; ++i) {
            float4 v = *(const float4*)(red + (tx + 32 * i) * 4);
            t.x += v.x; t.y += v.y; t.z += v.z; t.w += v.w;
        }
        atomAddF(&gsum[tx * 4 + 0], t.x);
        atomAddF(&gsum[tx * 4 + 1], t.y);
        atomAddF(&gsum[tx * 4 + 2], t.z);
        atomAddF(&gsum[tx * 4 + 3], t.w);
    }
    __syncthreads();
    *(float4*)(red + tx * 4) = q;
    __syncthreads();
    if (tx < 32) {
        float4 t = make_float4(0.f, 0.f, 0.f, 0.f);
#pragma unroll
        for (int i = 0; i < 8; ++i) {
            float4 v = *(const float4*)(red + (tx + 32 * i) * 4);
            t.x += v.x; t.y += v.y; t.z += v.z; t.w += v.w;
        }
        atomAddF(&gsq[tx * 4 + 0], t.x);
        atomAddF(&gsq[tx * 4 + 1], t.y);
        atomAddF(&gsq[tx * 4 + 2], t.z);
        atomAddF(&gsq[tx * 4 + 3], t.w);
    }
}

// ---------------- stats -> scale/shift ----------------
__global__ void finalize_stats(const float* __restrict__ stats,  // [sumV,sqV,sumC,sqC] x128
                               const float* __restrict__ wv, const float* __restrict__ bv, const float* __restrict__ msv,
                               const float* __restrict__ wc, const float* __restrict__ bc, const float* __restrict__ msc,
                               int Nvar, int Ncon,
                               float* __restrict__ scale_var, float* __restrict__ shift_var,
                               float* __restrict__ scale_con, float* __restrict__ shift_con) {
    int tx = threadIdx.x;
    if (tx < 128) {
        float n = (float)Nvar;
        float mu = stats[tx] / n;
        float ex2 = stats[128 + tx] / n;
        float ms = msv[tx];
        float var = ex2 - 2.f * ms * mu * mu + ms * ms * mu * mu;
        float istd = rsqrtf(var + 1e-5f);
        float sc = wv[tx] * istd;
        scale_var[tx] = sc;
        shift_var[tx] = bv[tx] - sc * ms * mu;
    } else if (tx < 256) {
        int t = tx - 128;
        float n = (float)Ncon;
        float mu = stats[256 + t] / n;
        float ex2 = stats[384 + t] / n;
        float ms = msc[t];
        float var = ex2 - 2.f * ms * mu * mu + ms * ms * mu * mu;
        float istd = rsqrtf(var + 1e-5f);
        float sc = wc[t] * istd;
        scale_con[t] = sc;
        shift_con[t] = bc[t] - sc * ms * mu;
    }
}

// ---------------- in-place normalize + relu ----------------
__global__ void norm_relu(float* __restrict__ buf,
                          const float* __restrict__ scale, const float* __restrict__ shift,
                          long nvec) {
    long i = (long)blockIdx.x * blockDim.x + threadIdx.x;
    if (i >= nvec) return;
    int q = ((int)i & 31) * 4;
    float4 v = *(float4*)(buf + i * 4);
    float4 o;
    o.x = fmaxf(0.f, v.x * scale[q + 0] + shift[q + 0]);
    o.y = fmaxf(0.f, v.y * scale[q + 1] + shift[q + 1]);
    o.z = fmaxf(0.f, v.z * scale[q + 2] + shift[q + 2]);
    o.w = fmaxf(0.f, v.w * scale[q + 3] + shift[q + 3]);
    *(float4*)(buf + i * 4) = o;
}

extern "C" void kernel_launch(void* const* d_in, const int* in_sizes, int n_in,
                              void* d_out, int out_size, void* d_ws, size_t ws_size,
                              hipStream_t stream) {
    const float* x_var = (const float*)d_in[0];
    const float* x_con = (const float*)d_in[1];
    const float* x_reg = (const float*)d_in[2];
    const int* src_adj = (const int*)d_in[3];
    const int* dst_adj = (const int*)d_in[4];
    const int* src_t   = (const int*)d_in[5];
    const int* dst_t   = (const int*)d_in[6];
    const int* src_g   = (const int*)d_in[7];
    const int* dst_g   = (const int*)d_in[8];
    const float* W_rel_adj  = (const float*)d_in[9];
    const float* b_adj      = (const float*)d_in[10];
    const float* W_root_adj = (const float*)d_in[11];
    const float* W_rel_t    = (const float*)d_in[12];
    const float* b_t        = (const float*)d_in[13];
    const float* W_root_t   = (const float*)d_in[14];
    const float* W_rel_g    = (const float*)d_in[15];
    const float* b_g        = (const float*)d_in[16];
    const float* W_root_g   = (const float*)d_in[17];
    const float* gnw_v  = (const float*)d_in[18];
    const float* gnb_v  = (const float*)d_in[19];
    const float* gnms_v = (const float*)d_in[20];
    const float* gnw_c  = (const float*)d_in[21];
    const float* gnb_c  = (const float*)d_in[22];
    const float* gnms_c = (const float*)d_in[23];

    const int Nvar = in_sizes[0] / D;
    const int Ncon = in_sizes[1] / D;
    const int Eadj = in_sizes[3];
    const int Et   = in_sizes[5];
    const int Eg   = in_sizes[7];
    const int Emax = Eadj > Et ? (Eadj > Eg ? Eadj : Eg) : (Et > Eg ? Et : Eg);

    // ---- workspace layout ----
    float* ws = (float*)d_ws;
    float* ybuf = ws;                                   // Nvar*128 floats (max src count)
    float* Wsum = ybuf + (size_t)Nvar * D;              // 16384
    float* bsum = Wsum + D * D;                         // 128
    float* stats = bsum + D;                            // 512
    float* scale_var = stats + 512;
    float* shift_var = scale_var + 128;
    float* scale_con = shift_var + 128;
    float* shift_con = scale_con + 128;
    int* cnt     = (int*)(shift_con + 128);             // Nvar ints (max dst count)
    int* buckets = cnt + Nvar;                          // Nvar*CAP ints
    int* ovf     = buckets + (size_t)Nvar * CAP;        // Emax ints
    int* ovf_cnt = ovf + Emax;                          // 1 int

    float* out_var = (float*)d_out;
    float* out_con = out_var + (size_t)Nvar * D;

    hipMemsetAsync(stats, 0, 512 * sizeof(float), stream);
    combine_wb<<<64, 256, 0, stream>>>(W_root_adj, W_root_g, Wsum, b_adj, b_g, bsum);

    // root terms: out = x @ W_root (+bias)
    gemm_nn<<<(Nvar + 127) / 128, 256, 0, stream>>>(Nvar, x_var, Wsum, bsum, out_var);
    gemm_nn<<<(Ncon + 127) / 128, 256, 0, stream>>>(Ncon, x_con, W_root_t, b_t, out_con);

    struct G { const float* xs; const float* W; const int* src; const int* dst; int E; int Nsrc; int Ndst; float* out; };
    G graphs[3] = {
        { x_var, W_rel_adj, src_adj, dst_adj, Eadj, Nvar, Nvar, out_var },
        { x_reg, W_rel_g,   src_g,   dst_g,   Eg,   -1,   Nvar, out_var },
        { x_var, W_rel_t,   src_t,   dst_t,   Et,   Nvar, Ncon, out_con },
    };
    graphs[1].Nsrc = in_sizes[2] / D;   // N_REG

    for (int gi = 0; gi < 3; ++gi) {
        G& g = graphs[gi];
        hipMemsetAsync(cnt, 0, (size_t)g.Ndst * sizeof(int), stream);
        hipMemsetAsync(ovf_cnt, 0, sizeof(int), stream);
        fill_buckets<<<(g.E + 255) / 256, 256, 0, stream>>>(g.src, g.dst, g.E, cnt, buckets, ovf, ovf_cnt);
        gemm_nn<<<(g.Nsrc + 127) / 128, 256, 0, stream>>>(g.Nsrc, g.xs, g.W, nullptr, ybuf);
        {
            long T = (long)g.Ndst * 64;
            pull_add<<<(int)((T + 255) / 256), 256, 0, stream>>>(ybuf, cnt, buckets, g.out, g.Ndst);
        }
        overflow_scatter<<<256, 256, 0, stream>>>(g.src, g.dst, ovf, ovf_cnt, ybuf, g.out);
    }

    col_stats<<<1024, 256, 0, stream>>>(out_var, Nvar, stats, stats + 128);
    col_stats<<<1024, 256, 0, stream>>>(out_con, Ncon, stats + 256, stats + 384);

    finalize_stats<<<1, 256, 0, stream>>>(stats,
        gnw_v, gnb_v, gnms_v, gnw_c, gnb_c, gnms_c,
        Nvar, Ncon, scale_var, shift_var, scale_con, shift_con);

    {
        long nvec = (long)Nvar * 32;
        norm_relu<<<(int)((nvec + 255) / 256), 256, 0, stream>>>(out_var, scale_var, shift_var, nvec);
    }
    {
        long nvec = (long)Ncon * 32;
        norm_relu<<<(int)((nvec + 255) / 256), 256, 0, stream>>>(out_con, scale_con, shift_con, nvec);
    }
}

// Round 3
// 962.387 us; speedup vs baseline: 4.2559x; 1.4293x over previous
//
#include <hip/hip_runtime.h>
#include <hip/hip_bf16.h>

#define D 128
#define CAP 40

typedef __attribute__((ext_vector_type(8))) short bf16x8;
typedef __attribute__((ext_vector_type(4))) float f32x4;

__device__ __forceinline__ void atomAddF(float* p, float v) { unsafeAtomicAdd(p, v); }

__device__ __forceinline__ unsigned short f2bf(float f) {
    __hip_bfloat16 h = __float2bfloat16(f);
    return *reinterpret_cast<unsigned short*>(&h);
}
__device__ __forceinline__ float bf2f(unsigned int u16) {
    unsigned int x = u16 << 16;
    return *reinterpret_cast<float*>(&x);
}

// ---------------- cast fp32 -> bf16, 4 elems/thread ----------------
__global__ void cast_bf16(const float* __restrict__ in, unsigned short* __restrict__ out, long n4) {
    long i = (long)blockIdx.x * blockDim.x + threadIdx.x;
    if (i >= n4) return;
    float4 v = ((const float4*)in)[i];
    ushort4 o;
    o.x = f2bf(v.x); o.y = f2bf(v.y); o.z = f2bf(v.z); o.w = f2bf(v.w);
    ((ushort4*)out)[i] = o;
}

// ---------------- weights: cast + transpose (Wt[n*128+k] = W[k*128+n]) ----------------
__global__ void prep_weights(const float* __restrict__ Wra, const float* __restrict__ Wrg,
                             const float* __restrict__ Wrt, const float* __restrict__ Wroot_t,
                             const float* __restrict__ Wroot_a, const float* __restrict__ Wroot_g,
                             const float* __restrict__ ba, const float* __restrict__ bg,
                             unsigned short* __restrict__ Wt_adj, unsigned short* __restrict__ Wt_g,
                             unsigned short* __restrict__ Wt_t, unsigned short* __restrict__ Wt_root_t,
                             unsigned short* __restrict__ Wt_sum, float* __restrict__ bsum) {
    int i = blockIdx.x * blockDim.x + threadIdx.x;
    if (i < D * D) {
        int k = i >> 7, n = i & 127;
        int ti = n * D + k;
        Wt_adj[ti]    = f2bf(Wra[i]);
        Wt_g[ti]      = f2bf(Wrg[i]);
        Wt_t[ti]      = f2bf(Wrt[i]);
        Wt_root_t[ti] = f2bf(Wroot_t[i]);
        Wt_sum[ti]    = f2bf(Wroot_a[i] + Wroot_g[i]);
    }
    if (i < D) bsum[i] = ba[i] + bg[i];
}

// ---------------- bucket build ----------------
__global__ void fill_buckets(const int* __restrict__ src, const int* __restrict__ dst, int E,
                             int* __restrict__ cnt, int* __restrict__ buckets,
                             int* __restrict__ ovf, int* __restrict__ ovf_cnt) {
    int e = blockIdx.x * blockDim.x + threadIdx.x;
    if (e >= E) return;
    int d = dst[e];
    int p = atomicAdd(&cnt[d], 1);
    if (p < CAP) buckets[(long)d * CAP + p] = src[e];
    else         ovf[atomicAdd(ovf_cnt, 1)] = e;
}

// ---------------- pull-aggregate (bf16): agg[d] = sum y[src_e], no atomics ----------------
// one wave per dst row; lane holds 2 columns (bf16x2 = 1 dword)
__launch_bounds__(256)
__global__ void pull_agg(const unsigned short* __restrict__ y,
                         const int* __restrict__ cnt, const int* __restrict__ buckets,
                         const int* __restrict__ src, const int* __restrict__ dst,
                         const int* __restrict__ ovf, const int* __restrict__ ovf_cnt,
                         unsigned short* __restrict__ agg, int N) {
    int wid = (int)(((long)blockIdx.x * blockDim.x + threadIdx.x) >> 6);
    int lane = threadIdx.x & 63;
    if (wid >= N) return;
    int m = cnt[wid];
    int mc = m > CAP ? CAP : m;
    int idx = (lane < mc) ? buckets[(long)wid * CAP + lane] : 0;
    float accx = 0.f, accy = 0.f;
    for (int j = 0; j < mc; ++j) {
        int s = __shfl(idx, j, 64);
        unsigned int raw = *(const unsigned int*)(y + (long)s * D + lane * 2);
        accx += bf2f(raw & 0xffffu);
        accy += bf2f(raw >> 16);
    }
    if (m > CAP) {                       // rare path: exact via overflow list scan
        int oc = *ovf_cnt;
        for (int i = 0; i < oc; ++i) {
            int e = ovf[i];
            if (dst[e] == wid) {
                int s = src[e];
                unsigned int raw = *(const unsigned int*)(y + (long)s * D + lane * 2);
                accx += bf2f(raw & 0xffffu);
                accy += bf2f(raw >> 16);
            }
        }
    }
    unsigned int o = (unsigned int)f2bf(accx) | ((unsigned int)f2bf(accy) << 16);
    *(unsigned int*)(agg + (long)wid * D + lane * 2) = o;
}

// ---------------- fused MFMA GEMM: out = sum_t A_t @ W_t + bias, + column stats ----------------
// block 256 = 4 waves; wave does 32 rows x 128 cols; 16x16x32 bf16 MFMA
__launch_bounds__(256)
__global__ void gemm_fused(int N,
                           const unsigned short* __restrict__ A0, const unsigned short* __restrict__ Wt0,
                           const unsigned short* __restrict__ A1, const unsigned short* __restrict__ Wt1,
                           const unsigned short* __restrict__ A2, const unsigned short* __restrict__ Wt2,
                           int nTerms,
                           const float* __restrict__ bias, float* __restrict__ out,
                           float* __restrict__ gsum, float* __restrict__ gsq) {
    __shared__ float sstat[256];
    const int tx = threadIdx.x;
    sstat[tx] = 0.f;
    __syncthreads();

    const int wave = tx >> 6, lane = tx & 63;
    const int quad = lane >> 4, l16 = lane & 15;
    const int row0 = blockIdx.x * 128 + wave * 32;

    f32x4 acc[2][8];
#pragma unroll
    for (int rt = 0; rt < 2; ++rt)
#pragma unroll
        for (int ct = 0; ct < 8; ++ct)
#pragma unroll
            for (int i = 0; i < 4; ++i) acc[rt][ct][i] = 0.f;

    const unsigned short* As[3] = {A0, A1, A2};
    const unsigned short* Ws[3] = {Wt0, Wt1, Wt2};

    for (int t = 0; t < nTerms; ++t) {
        const unsigned short* __restrict__ A = As[t];
        const unsigned short* __restrict__ Wt = Ws[t];
#pragma unroll
        for (int ks = 0; ks < 4; ++ks) {
            const int k0 = ks * 32;
            bf16x8 a[2];
#pragma unroll
            for (int rt = 0; rt < 2; ++rt) {
                int r = row0 + rt * 16 + l16;
                if (r < N) {
                    a[rt] = *(const bf16x8*)(A + (size_t)r * D + k0 + quad * 8);
                } else {
#pragma unroll
                    for (int j = 0; j < 8; ++j) a[rt][j] = 0;
                }
            }
#pragma unroll
            for (int ct = 0; ct < 8; ++ct) {
                bf16x8 b = *(const bf16x8*)(Wt + (size_t)(ct * 16 + l16) * D + k0 + quad * 8);
                acc[0][ct] = __builtin_amdgcn_mfma_f32_16x16x32_bf16(a[0], b, acc[0][ct], 0, 0, 0);
                acc[1][ct] = __builtin_amdgcn_mfma_f32_16x16x32_bf16(a[1], b, acc[1][ct], 0, 0, 0);
            }
        }
    }

    // epilogue: bias, store, per-column partial stats
    float bv[8];
#pragma unroll
    for (int ct = 0; ct < 8; ++ct) bv[ct] = bias[ct * 16 + l16];

    float psum[8], psq[8];
#pragma unroll
    for (int ct = 0; ct < 8; ++ct) { psum[ct] = 0.f; psq[ct] = 0.f; }

#pragma unroll
    for (int rt = 0; rt < 2; ++rt)
#pragma unroll
        for (int i = 0; i < 4; ++i) {
            int row = row0 + rt * 16 + quad * 4 + i;
            if (row < N) {
#pragma unroll
                for (int ct = 0; ct < 8; ++ct) {
                    float v = acc[rt][ct][i] + bv[ct];
                    out[(size_t)row * D + ct * 16 + l16] = v;
                    psum[ct] += v;
                    psq[ct] += v * v;
                }
            }
        }

#pragma unroll
    for (int ct = 0; ct < 8; ++ct) {
        atomicAdd(&sstat[ct * 16 + l16], psum[ct]);
        atomicAdd(&sstat[128 + ct * 16 + l16], psq[ct]);
    }
    __syncthreads();
    if (tx < 128) {
        atomAddF(&gsum[tx], sstat[tx]);
        atomAddF(&gsq[tx], sstat[128 + tx]);
    }
}

// ---------------- stats -> scale/shift ----------------
__global__ void finalize_stats(const float* __restrict__ stats,
                               const float* __restrict__ wv, const float* __restrict__ bv, const float* __restrict__ msv,
                               const float* __restrict__ wc, const float* __restrict__ bc, const float* __restrict__ msc,
                               int Nvar, int Ncon,
                               float* __restrict__ scale_var, float* __restrict__ shift_var,
                               float* __restrict__ scale_con, float* __restrict__ shift_con) {
    int tx = threadIdx.x;
    if (tx < 128) {
        float n = (float)Nvar;
        float mu = stats[tx] / n;
        float ex2 = stats[128 + tx] / n;
        float ms = msv[tx];
        float var = ex2 - 2.f * ms * mu * mu + ms * ms * mu * mu;
        float istd = rsqrtf(var + 1e-5f);
        float sc = wv[tx] * istd;
        scale_var[tx] = sc;
        shift_var[tx] = bv[tx] - sc * ms * mu;
    } else if (tx < 256) {
        int t = tx - 128;
        float n = (float)Ncon;
        float mu = stats[256 + t] / n;
        float ex2 = stats[384 + t] / n;
        float ms = msc[t];
        float var = ex2 - 2.f * ms * mu * mu + ms * ms * mu * mu;
        float istd = rsqrtf(var + 1e-5f);
        float sc = wc[t] * istd;
        scale_con[t] = sc;
        shift_con[t] = bc[t] - sc * ms * mu;
    }
}

// ---------------- in-place normalize + relu ----------------
__global__ void norm_relu(float* __restrict__ buf,
                          const float* __restrict__ scale, const float* __restrict__ shift,
                          long nvec) {
    long i = (long)blockIdx.x * blockDim.x + threadIdx.x;
    if (i >= nvec) return;
    int q = ((int)i & 31) * 4;
    float4 v = *(float4*)(buf + i * 4);
    float4 o;
    o.x = fmaxf(0.f, v.x * scale[q + 0] + shift[q + 0]);
    o.y = fmaxf(0.f, v.y * scale[q + 1] + shift[q + 1]);
    o.z = fmaxf(0.f, v.z * scale[q + 2] + shift[q + 2]);
    o.w = fmaxf(0.f, v.w * scale[q + 3] + shift[q + 3]);
    *(float4*)(buf + i * 4) = o;
}

extern "C" void kernel_launch(void* const* d_in, const int* in_sizes, int n_in,
                              void* d_out, int out_size, void* d_ws, size_t ws_size,
                              hipStream_t stream) {
    const float* x_var = (const float*)d_in[0];
    const float* x_con = (const float*)d_in[1];
    const float* x_reg = (const float*)d_in[2];
    const int* src_adj = (const int*)d_in[3];
    const int* dst_adj = (const int*)d_in[4];
    const int* src_t   = (const int*)d_in[5];
    const int* dst_t   = (const int*)d_in[6];
    const int* src_g   = (const int*)d_in[7];
    const int* dst_g   = (const int*)d_in[8];
    const float* W_rel_adj  = (const float*)d_in[9];
    const float* b_adj      = (const float*)d_in[10];
    const float* W_root_adj = (const float*)d_in[11];
    const float* W_rel_t    = (const float*)d_in[12];
    const float* b_t        = (const float*)d_in[13];
    const float* W_root_t   = (const float*)d_in[14];
    const float* W_rel_g    = (const float*)d_in[15];
    const float* b_g        = (const float*)d_in[16];
    const float* W_root_g   = (const float*)d_in[17];
    const float* gnw_v  = (const float*)d_in[18];
    const float* gnb_v  = (const float*)d_in[19];
    const float* gnms_v = (const float*)d_in[20];
    const float* gnw_c  = (const float*)d_in[21];
    const float* gnb_c  = (const float*)d_in[22];
    const float* gnms_c = (const float*)d_in[23];

    const int Nvar = in_sizes[0] / D;
    const int Ncon = in_sizes[1] / D;
    const int Nreg = in_sizes[2] / D;
    const int Eadj = in_sizes[3];
    const int Et   = in_sizes[5];
    const int Eg   = in_sizes[7];
    const int Emax = Eadj > Et ? (Eadj > Eg ? Eadj : Eg) : (Et > Eg ? Et : Eg);

    // ---- workspace layout (large blocks first, all 256B-aligned) ----
    char* p = (char*)d_ws;
    unsigned short* xv_bf = (unsigned short*)p; p += (size_t)Nvar * D * 2;
    unsigned short* xc_bf = (unsigned short*)p; p += (size_t)Ncon * D * 2;
    unsigned short* xr_bf = (unsigned short*)p; p += (size_t)Nreg * D * 2;
    unsigned short* agg_adj = (unsigned short*)p; p += (size_t)Nvar * D * 2;
    unsigned short* agg_g   = (unsigned short*)p; p += (size_t)Nvar * D * 2;
    unsigned short* agg_t   = (unsigned short*)p; p += (size_t)Ncon * D * 2;
    int* buckets = (int*)p; p += (size_t)Nvar * CAP * 4;
    int* ovf     = (int*)p; p += (size_t)Emax * 4;
    int* cnt     = (int*)p; p += (size_t)Nvar * 4;
    unsigned short* Wt_adj    = (unsigned short*)p; p += D * D * 2;
    unsigned short* Wt_g      = (unsigned short*)p; p += D * D * 2;
    unsigned short* Wt_t      = (unsigned short*)p; p += D * D * 2;
    unsigned short* Wt_root_t = (unsigned short*)p; p += D * D * 2;
    unsigned short* Wt_sum    = (unsigned short*)p; p += D * D * 2;
    float* bsum  = (float*)p; p += D * 4;
    float* stats = (float*)p; p += 512 * 4;
    float* scale_var = (float*)p; p += D * 4;
    float* shift_var = (float*)p; p += D * 4;
    float* scale_con = (float*)p; p += D * 4;
    float* shift_con = (float*)p; p += D * 4;
    int* ovf_cnt = (int*)p; p += 256;

    float* out_var = (float*)d_out;
    float* out_con = out_var + (size_t)Nvar * D;

    hipMemsetAsync(stats, 0, 512 * sizeof(float), stream);
    prep_weights<<<64, 256, 0, stream>>>(W_rel_adj, W_rel_g, W_rel_t, W_root_t,
                                         W_root_adj, W_root_g, b_adj, b_g,
                                         Wt_adj, Wt_g, Wt_t, Wt_root_t, Wt_sum, bsum);

    cast_bf16<<<(int)(((long)Nvar * 32 + 255) / 256), 256, 0, stream>>>(x_var, xv_bf, (long)Nvar * 32);
    cast_bf16<<<(int)(((long)Ncon * 32 + 255) / 256), 256, 0, stream>>>(x_con, xc_bf, (long)Ncon * 32);
    cast_bf16<<<(int)(((long)Nreg * 32 + 255) / 256), 256, 0, stream>>>(x_reg, xr_bf, (long)Nreg * 32);

    struct G { const unsigned short* xs; const int* src; const int* dst; int E; int Ndst; unsigned short* agg; };
    G graphs[3] = {
        { xv_bf, src_adj, dst_adj, Eadj, Nvar, agg_adj },
        { xr_bf, src_g,   dst_g,   Eg,   Nvar, agg_g   },
        { xv_bf, src_t,   dst_t,   Et,   Ncon, agg_t   },
    };

    for (int gi = 0; gi < 3; ++gi) {
        G& g = graphs[gi];
        hipMemsetAsync(cnt, 0, (size_t)g.Ndst * sizeof(int), stream);
        hipMemsetAsync(ovf_cnt, 0, sizeof(int), stream);
        fill_buckets<<<(g.E + 255) / 256, 256, 0, stream>>>(g.src, g.dst, g.E, cnt, buckets, ovf, ovf_cnt);
        long T = (long)g.Ndst * 64;
        pull_agg<<<(int)((T + 255) / 256), 256, 0, stream>>>(g.xs, cnt, buckets,
                                                             g.src, g.dst, ovf, ovf_cnt,
                                                             g.agg, g.Ndst);
    }

    gemm_fused<<<(Nvar + 127) / 128, 256, 0, stream>>>(Nvar,
        agg_adj, Wt_adj, agg_g, Wt_g, xv_bf, Wt_sum, 3,
        bsum, out_var, stats, stats + 128);
    gemm_fused<<<(Ncon + 127) / 128, 256, 0, stream>>>(Ncon,
        agg_t, Wt_t, xc_bf, Wt_root_t, nullptr, nullptr, 2,
        b_t, out_con, stats + 256, stats + 384);

    finalize_stats<<<1, 256, 0, stream>>>(stats,
        gnw_v, gnb_v, gnms_v, gnw_c, gnb_c, gnms_c,
        Nvar, Ncon, scale_var, shift_var, scale_con, shift_con);

    {
        long nvec = (long)Nvar * 32;
        norm_relu<<<(int)((nvec + 255) / 256), 256, 0, stream>>>(out_var, scale_var, shift_var, nvec);
    }
    {
        long nvec = (long)Ncon * 32;
        norm_relu<<<(int)((nvec + 255) / 256), 256, 0, stream>>>(out_con, scale_con, shift_con, nvec);
    }
}